// Round 1
// baseline (216.999 us; speedup 1.0000x reference)
//
#include <hip/hip_runtime.h>

#define BQ 2048
#define MM 65536
#define CC 128
#define NSPLIT 16
#define KCHUNK (MM/NSPLIT)
#define NQB (BQ/64)

typedef short short8 __attribute__((ext_vector_type(8)));
typedef float f32x4 __attribute__((ext_vector_type(4)));

__device__ __forceinline__ unsigned short f2bf(float x) {
    unsigned int u = __builtin_bit_cast(unsigned int, x);
    u = (u + 0x7FFFu + ((u >> 16) & 1u)) >> 16;
    return (unsigned short)u;
}

// ---------------- const prep: G = Kw@Kw^T, kb2 = key_b@Kw^T, etab = y_emb@W3 + msg_b ----
__global__ __launch_bounds__(128) void prep_const_kernel(
    const float* __restrict__ keyw, const float* __restrict__ keyb,
    const float* __restrict__ msgw, const float* __restrict__ msgb,
    const float* __restrict__ yemb,
    float* __restrict__ G, float* __restrict__ kb2, float* __restrict__ etab)
{
    __shared__ float rowd[128];
    int t = threadIdx.x;
    int d = blockIdx.x;
    if (d < 128) {
        rowd[t] = keyw[d*128 + t];
        __syncthreads();
        float acc = 0.f;
        for (int c2 = 0; c2 < 128; ++c2) acc = fmaf(rowd[c2], keyw[t*128 + c2], acc);
        G[d*128 + t] = acc;
    } else if (d == 128) {
        rowd[t] = keyb[t];
        __syncthreads();
        float acc = 0.f;
        for (int c2 = 0; c2 < 128; ++c2) acc = fmaf(rowd[c2], keyw[t*128 + c2], acc);
        kb2[t] = acc;
    } else {
        float acc0 = msgb[t], acc1 = msgb[t];
        for (int c2 = 0; c2 < 128; ++c2) {
            float w3 = msgw[(256 + c2)*128 + t];
            acc0 = fmaf(yemb[c2], w3, acc0);
            acc1 = fmaf(yemb[128 + c2], w3, acc1);
        }
        etab[t] = acc0;
        etab[128 + t] = acc1;
    }
}

// ---------------- memory l2norm -> xhat (bf16 row-major) + xhatT (bf16 transposed) ------
__global__ __launch_bounds__(256) void mem_norm_kernel(
    const float* __restrict__ mx,
    unsigned short* __restrict__ xhat, unsigned short* __restrict__ xhatT)
{
    __shared__ __align__(16) float tile[64*132];
    __shared__ float rs[64];
    __shared__ float invn[64];
    const int t = threadIdx.x;
    const int lane = t & 63;
    const int kb0 = blockIdx.x * 64;

    float4 vals[8];
    int rows[8];
    #pragma unroll
    for (int i = 0; i < 8; ++i) {
        int idx = t + 256*i;            // float4 id 0..2047
        int e = idx * 4;
        int row = e >> 7, col = e & 127;
        float4 v = *(const float4*)(mx + (size_t)kb0*CC + e);
        vals[i] = v; rows[i] = row;
        *(float4*)&tile[row*132 + col] = v;
        float s = v.x*v.x + v.y*v.y + v.z*v.z + v.w*v.w;
        #pragma unroll
        for (int m2 = 1; m2 < 32; m2 <<= 1) s += __shfl_xor(s, m2, 64);
        if ((lane & 31) == 0) rs[row] = s;   // exactly one writer per row
    }
    __syncthreads();
    if (t < 64) invn[t] = 1.0f / fmaxf(sqrtf(rs[t]), 1e-12f);
    __syncthreads();
    // xhat row-major
    #pragma unroll
    for (int i = 0; i < 8; ++i) {
        float sc = invn[rows[i]];
        float4 v = vals[i];
        ushort4 o;
        o.x = f2bf(v.x*sc); o.y = f2bf(v.y*sc); o.z = f2bf(v.z*sc); o.w = f2bf(v.w*sc);
        int idx = t + 256*i;
        *(ushort4*)(xhat + (size_t)kb0*CC + idx*4) = o;
    }
    // xhatT [c][m]
    {
        int c = t >> 1, h = t & 1;
        #pragma unroll
        for (int seg = 0; seg < 4; ++seg) {
            unsigned int pk[4];
            #pragma unroll
            for (int j = 0; j < 4; ++j) {
                int k0 = h*32 + seg*8 + j*2;
                unsigned int lo = f2bf(tile[k0*132 + c] * invn[k0]);
                unsigned int hi = f2bf(tile[(k0+1)*132 + c] * invn[k0+1]);
                pk[j] = lo | (hi << 16);
            }
            uint4 v; v.x = pk[0]; v.y = pk[1]; v.z = pk[2]; v.w = pk[3];
            *(uint4*)(xhatT + (size_t)c*MM + kb0 + h*32 + seg*8) = v;
        }
    }
}

// ---------------- query prep: q2 = (l2norm(f)@G + kb2)*log2e (bf16), a = f@W1 (f32) ----
__global__ __launch_bounds__(256) void query_prep_kernel(
    const float* __restrict__ feat, const float* __restrict__ G,
    const float* __restrict__ kb2, const float* __restrict__ msgw,
    unsigned short* __restrict__ q2, float* __restrict__ a)
{
    __shared__ float fl[4][128];
    const int t = threadIdx.x;
    const int w = t >> 6;
    const int lane = t & 63;
    const int b = blockIdx.x*4 + w;
    const int j0 = lane, j1 = lane + 64;
    float f0 = feat[b*CC + j0], f1 = feat[b*CC + j1];
    fl[w][j0] = f0; fl[w][j1] = f1;
    float s = f0*f0 + f1*f1;
    #pragma unroll
    for (int m2 = 1; m2 < 64; m2 <<= 1) s += __shfl_xor(s, m2, 64);
    float invn = 1.0f / fmaxf(sqrtf(s), 1e-12f);
    __syncthreads();
    float g0 = 0.f, g1 = 0.f, a0 = 0.f, a1 = 0.f;
    for (int i = 0; i < 128; ++i) {
        float x = fl[w][i];
        g0 = fmaf(x, G[i*128 + j0], g0);
        g1 = fmaf(x, G[i*128 + j1], g1);
        a0 = fmaf(x, msgw[i*128 + j0], a0);
        a1 = fmaf(x, msgw[i*128 + j1], a1);
    }
    const float LOG2E = 1.4426950408889634f;
    q2[b*CC + j0] = f2bf((g0*invn + kb2[j0]) * LOG2E);
    q2[b*CC + j1] = f2bf((g1*invn + kb2[j1]) * LOG2E);
    a[b*CC + j0] = a0;
    a[b*CC + j1] = a1;
}

// ---------------- flash attention: per (q-block 64, M-chunk 4096) partials --------------
__global__ __launch_bounds__(256, 2) void attn_kernel(
    const unsigned short* __restrict__ xhat,
    const unsigned short* __restrict__ xhatT,
    const unsigned short* __restrict__ q2,
    const float* __restrict__ seed_time,
    const float* __restrict__ mst,
    const int* __restrict__ memy,
    float* __restrict__ Upart,
    float* __restrict__ lpart,
    float* __restrict__ wypart)
{
    __shared__ __align__(16) unsigned short K_lds[64*128];   // swizzled, 16 KB
    __shared__ __align__(16) unsigned short VT_lds[128*64];  // swizzled, 16 KB
    __shared__ __align__(16) unsigned short P_lds[4][16*72]; // per-wave P, stride 72
    __shared__ float mst_lds[64];
    __shared__ float yf_lds[64];

    const int tid = threadIdx.x;
    const int w = tid >> 6;
    const int lane = tid & 63;
    const int g = lane >> 4;
    const int l15 = lane & 15;
    const int qb = blockIdx.x;       // 0..31
    const int chunk = blockIdx.y;    // 0..15
    const int qrow0 = qb*64 + w*16;

    // Q2 fragments in registers (A operand: row = lane&15, k = g*8 + i)
    short8 qf[4];
    #pragma unroll
    for (int cs = 0; cs < 4; ++cs)
        qf[cs] = *(const short8*)(q2 + (qrow0 + l15)*CC + cs*32 + g*8);

    float seed_r[4];
    #pragma unroll
    for (int r = 0; r < 4; ++r) seed_r[r] = seed_time[qrow0 + g*4 + r];

    f32x4 accU[8];
    #pragma unroll
    for (int n = 0; n < 8; ++n) accU[n] = (f32x4)0.f;
    float accl[4] = {0.f, 0.f, 0.f, 0.f};
    float accw[4] = {0.f, 0.f, 0.f, 0.f};

    for (int kt2 = 0; kt2 < KCHUNK/64; ++kt2) {
        const int kb0 = chunk*KCHUNK + kt2*64;
        __syncthreads();
        // stage K tile [64 keys][128 c], XOR-swizzled
        #pragma unroll
        for (int i = 0; i < 4; ++i) {
            int cid = tid + i*256;           // 0..1023
            int row = cid >> 4, cc = cid & 15;
            uint4 v = *(const uint4*)(xhat + (size_t)(kb0 + row)*CC + cc*8);
            *(uint4*)((char*)K_lds + row*256 + ((cc*16) ^ ((row & 7) << 4))) = v;
        }
        // stage V^T tile [128 c][64 keys], XOR-swizzled
        #pragma unroll
        for (int i = 0; i < 4; ++i) {
            int cid = tid + i*256;
            int c = cid >> 3, cc = cid & 7;
            uint4 v = *(const uint4*)(xhatT + (size_t)c*MM + kb0 + cc*8);
            *(uint4*)((char*)VT_lds + c*128 + ((cc*16) ^ ((c & 7) << 4))) = v;
        }
        if (tid < 64) {
            mst_lds[tid] = mst[kb0 + tid];
            yf_lds[tid] = (float)memy[kb0 + tid];
        }
        __syncthreads();

        // S = q2 @ xhat^T (16q x 64k per wave), then P = exp2(S) masked
        #pragma unroll
        for (int sub = 0; sub < 4; ++sub) {
            f32x4 s = (f32x4)0.f;
            const int key = sub*16 + l15;
            #pragma unroll
            for (int cs = 0; cs < 4; ++cs) {
                short8 kf = *(const short8*)((const char*)K_lds + key*256 +
                                             ((cs*64 + g*16) ^ ((key & 7) << 4)));
                s = __builtin_amdgcn_mfma_f32_16x16x32_bf16(qf[cs], kf, s, 0, 0, 0);
            }
            float mstv = mst_lds[key];
            float yv = yf_lds[key];
            #pragma unroll
            for (int r = 0; r < 4; ++r) {
                float p = (seed_r[r] < mstv) ? 0.f : exp2f(s[r]);
                accl[r] += p;
                accw[r] += p * yv;
                P_lds[w][(g*4 + r)*72 + key] = f2bf(p);
            }
        }
        asm volatile("s_waitcnt lgkmcnt(0)" ::: "memory");
        // U += P @ xhat  (A from P_lds, B from VT_lds)
        #pragma unroll
        for (int kk = 0; kk < 2; ++kk) {
            short8 pa = *(const short8*)((const char*)&P_lds[w][0] + l15*144 + kk*64 + g*16);
            #pragma unroll
            for (int n = 0; n < 8; ++n) {
                const int c = n*16 + l15;
                short8 vf = *(const short8*)((const char*)VT_lds + c*128 +
                                             ((kk*64 + g*16) ^ ((c & 7) << 4)));
                accU[n] = __builtin_amdgcn_mfma_f32_16x16x32_bf16(pa, vf, accU[n], 0, 0, 0);
            }
        }
    }

    // epilogue: partial sums out
    const int rbase = (qb*NSPLIT + chunk)*64 + w*16;
    #pragma unroll
    for (int r = 0; r < 4; ++r) {
        float lv = accl[r], wv = accw[r];
        #pragma unroll
        for (int m2 = 1; m2 < 16; m2 <<= 1) {
            lv += __shfl_xor(lv, m2, 64);
            wv += __shfl_xor(wv, m2, 64);
        }
        if (l15 == 0) {
            lpart[rbase + g*4 + r] = lv;
            wypart[rbase + g*4 + r] = wv;
        }
    }
    #pragma unroll
    for (int n = 0; n < 8; ++n) {
        #pragma unroll
        for (int r = 0; r < 4; ++r)
            Upart[(size_t)(rbase + g*4 + r)*CC + n*16 + l15] = accU[n][r];
    }
}

// ---------------- combine split-M partials --------------------------------------------
__global__ __launch_bounds__(256) void combine_l_kernel(
    const float* __restrict__ lpart, const float* __restrict__ wypart,
    float* __restrict__ ls, float* __restrict__ s1)
{
    int b = blockIdx.x*256 + threadIdx.x;
    int qb = b >> 6, r = b & 63;
    float l = 0.f, wy = 0.f;
    for (int s2 = 0; s2 < NSPLIT; ++s2) {
        int o = (qb*NSPLIT + s2)*64 + r;
        l += lpart[o];
        wy += wypart[o];
    }
    ls[b] = l;
    s1[b] = wy / l;
}

__global__ __launch_bounds__(256) void combine_U_kernel(
    const float* __restrict__ Upart, float* __restrict__ hpre)
{
    int idx = blockIdx.x*256 + threadIdx.x;  // 0..B*C-1
    int b = idx >> 7, c = idx & 127;
    int qb = b >> 6, r = b & 63;
    float u = 0.f;
    for (int s2 = 0; s2 < NSPLIT; ++s2)
        u += Upart[(size_t)((qb*NSPLIT + s2)*64 + r)*CC + c];
    hpre[idx] = u;
}

// ---------------- fused epilogue MLP ---------------------------------------------------
__global__ __launch_bounds__(256) void final_kernel(
    const float* __restrict__ feat, const float* __restrict__ hpre,
    const float* __restrict__ ls, const float* __restrict__ s1v,
    const float* __restrict__ a, const float* __restrict__ etab,
    const float* __restrict__ msgw,
    const float* __restrict__ uw1, const float* __restrict__ ub1,
    const float* __restrict__ uw2, const float* __restrict__ ub2,
    float* __restrict__ out)
{
    __shared__ float fl[4][128], t0[4][128], t1l[4][128];
    const int t = threadIdx.x;
    const int w = t >> 6;
    const int lane = t & 63;
    const int b = blockIdx.x*4 + w;
    const int j0 = lane, j1 = lane + 64;
    float f0 = feat[b*CC + j0], f1 = feat[b*CC + j1];
    fl[w][j0] = f0; fl[w][j1] = f1;
    t0[w][j0] = hpre[b*CC + j0];
    t0[w][j1] = hpre[b*CC + j1];
    __syncthreads();
    float linv = 1.0f / ls[b];
    float s1 = s1v[b];
    float acc0 = 0.f, acc1 = 0.f;
    for (int i = 0; i < 128; ++i) {
        float x = t0[w][i];
        acc0 = fmaf(x, msgw[(128 + i)*128 + j0], acc0);
        acc1 = fmaf(x, msgw[(128 + i)*128 + j1], acc1);
    }
    float mix0 = (1.f - s1)*etab[j0] + s1*etab[128 + j0];
    float mix1 = (1.f - s1)*etab[j1] + s1*etab[128 + j1];
    float hg0 = a[b*CC + j0] + acc0*linv + mix0;
    float hg1 = a[b*CC + j1] + acc1*linv + mix1;
    __syncthreads();
    t0[w][j0] = hg0; t0[w][j1] = hg1;
    __syncthreads();
    float h0 = ub1[j0], h1 = ub1[j1];
    for (int i = 0; i < 128; ++i) {
        float xf = fl[w][i];
        float xh = t0[w][i];
        h0 = fmaf(xf, uw1[i*128 + j0], h0);
        h1 = fmaf(xf, uw1[i*128 + j1], h1);
        h0 = fmaf(xh, uw1[(128 + i)*128 + j0], h0);
        h1 = fmaf(xh, uw1[(128 + i)*128 + j1], h1);
    }
    h0 = fmaxf(h0, 0.f); h1 = fmaxf(h1, 0.f);
    t1l[w][j0] = h0; t1l[w][j1] = h1;
    __syncthreads();
    float o0 = ub2[j0], o1 = ub2[j1];
    for (int i = 0; i < 128; ++i) {
        float x = t1l[w][i];
        o0 = fmaf(x, uw2[i*128 + j0], o0);
        o1 = fmaf(x, uw2[i*128 + j1], o1);
    }
    out[b*CC + j0] = f0 + o0;
    out[b*CC + j1] = f1 + o1;
}

extern "C" void kernel_launch(void* const* d_in, const int* in_sizes, int n_in,
                              void* d_out, int out_size, void* d_ws, size_t ws_size,
                              hipStream_t stream) {
    (void)in_sizes; (void)n_in; (void)out_size; (void)ws_size;
    const float* feature  = (const float*)d_in[0];
    const float* memory_x = (const float*)d_in[1];
    const int*   memory_y = (const int*)d_in[2];
    const float* seed_t   = (const float*)d_in[3];
    const float* mem_st   = (const float*)d_in[4];
    const float* key_w    = (const float*)d_in[5];
    const float* key_b    = (const float*)d_in[6];
    const float* msg_w    = (const float*)d_in[7];
    const float* msg_b    = (const float*)d_in[8];
    const float* upd_w1   = (const float*)d_in[9];
    const float* upd_b1   = (const float*)d_in[10];
    const float* upd_w2   = (const float*)d_in[11];
    const float* upd_b2   = (const float*)d_in[12];
    const float* y_emb    = (const float*)d_in[13];
    float* out = (float*)d_out;

    char* ws = (char*)d_ws;
    unsigned short* xhat  = (unsigned short*)(ws + 0);          // 16 MB
    unsigned short* xhatT = (unsigned short*)(ws + 16777216);   // 16 MB
    unsigned short* q2    = (unsigned short*)(ws + 33554432);   // 512 KB
    float* a      = (float*)(ws + 34078720);                    // 1 MB
    float* G      = (float*)(ws + 35127296);                    // 64 KB
    float* kb2    = (float*)(ws + 35192832);                    // 512 B
    float* etab   = (float*)(ws + 35193344);                    // 1 KB
    float* lsv    = (float*)(ws + 35194368);                    // 8 KB
    float* s1v    = (float*)(ws + 35202560);                    // 8 KB
    float* hpre   = (float*)(ws + 35210752);                    // 1 MB
    float* lpart  = (float*)(ws + 36259328);                    // 128 KB
    float* wypart = (float*)(ws + 36390400);                    // 128 KB
    float* Upart  = (float*)(ws + 36521472);                    // 16 MB

    prep_const_kernel<<<130, 128, 0, stream>>>(key_w, key_b, msg_w, msg_b, y_emb, G, kb2, etab);
    mem_norm_kernel<<<MM/64, 256, 0, stream>>>(memory_x, xhat, xhatT);
    query_prep_kernel<<<BQ/4, 256, 0, stream>>>(feature, G, kb2, msg_w, q2, a);
    attn_kernel<<<dim3(NQB, NSPLIT), 256, 0, stream>>>(xhat, xhatT, q2, seed_t, mem_st,
                                                       memory_y, Upart, lpart, wypart);
    combine_l_kernel<<<BQ/256, 256, 0, stream>>>(lpart, wypart, lsv, s1v);
    combine_U_kernel<<<(BQ*CC)/256, 256, 0, stream>>>(Upart, hpre);
    final_kernel<<<BQ/4, 256, 0, stream>>>(feature, hpre, lsv, s1v, a, etab, msg_w,
                                           upd_w1, upd_b1, upd_w2, upd_b2, out);
}